// Round 1
// baseline (53.994 us; speedup 1.0000x reference)
//
#include <hip/hip_runtime.h>

// Per-pair math:
//   e = exp(-((x-cx)^2 w0^2 + (y-cy)^2 w1^2 + (z-cz)^2 w2^2))
// With w'_k = w_k * sqrt(log2(e)):
//   t_k = fma(x_k, w'_k, -c_k*w'_k);  e = exp2(-(t0^2+t1^2+t2^2))
// Derivative term: -2*x1_k*w_k^2*h*e = t_k * (-2*ln2*h*w'_k) * e
static constexpr float SQRT_LOG2E = 1.2011224087864498f;   // sqrt(log2(e))
static constexpr float NEG_2LN2   = -1.3862943611198906f;  // -2*ln(2)

template <int SET>  // 0: ux,uy,uz   1: P,Px   2: Q,Qy   3: R,Rz
__device__ __forceinline__ void srbf_body(
    const float* __restrict__ x, const float* __restrict__ h,
    const float* __restrict__ c, const float* __restrict__ w,
    float* __restrict__ out, int N, int N1, float4* lds)
{
    constexpr int REC = (SET == 0) ? 3 : 2;   // float4 records per center
    const int tid = threadIdx.x;

    // ---- stage per-center constants into LDS (once per block) ----
    for (int j = tid; j < N1; j += 256) {
        float hj  = h[j];
        float w0  = w[3 * j + 0] * SQRT_LOG2E;
        float w1  = w[3 * j + 1] * SQRT_LOG2E;
        float w2  = w[3 * j + 2] * SQRT_LOG2E;
        float cw0 = -c[3 * j + 0] * w0;
        float cw1 = -c[3 * j + 1] * w1;
        float cw2 = -c[3 * j + 2] * w2;
        if constexpr (SET == 0) {
            lds[j * 3 + 0] = make_float4(w0, w1, w2, cw0);
            lds[j * 3 + 1] = make_float4(cw1, cw2, NEG_2LN2 * hj * w0, NEG_2LN2 * hj * w1);
            lds[j * 3 + 2] = make_float4(NEG_2LN2 * hj * w2, 0.f, 0.f, 0.f);
        } else {
            constexpr int K = SET - 1;  // derivative dim: set1->x, set2->y, set3->z
            float wk = (K == 0) ? w0 : (K == 1 ? w1 : w2);
            lds[j * 2 + 0] = make_float4(w0, w1, w2, cw0);
            lds[j * 2 + 1] = make_float4(cw1, cw2, hj, NEG_2LN2 * hj * wk);
        }
    }
    __syncthreads();

    // ---- per-point accumulation over all centers ----
    const int i = blockIdx.x * 256 + tid;
    const float px = x[3 * i + 0], py = x[3 * i + 1], pz = x[3 * i + 2];
    float a0 = 0.f, a1 = 0.f, a2 = 0.f;

#pragma unroll 4
    for (int j = 0; j < N1; ++j) {
        const float4 A = lds[j * REC + 0];  // w0,w1,w2,cw0
        const float4 B = lds[j * REC + 1];  // cw1,cw2,(b0|h),(b1|b)
        float t0 = fmaf(px, A.x, A.w);
        float t1 = fmaf(py, A.y, B.x);
        float t2 = fmaf(pz, A.z, B.y);
        float s  = fmaf(t0, t0, fmaf(t1, t1, t2 * t2));
        float e  = __builtin_amdgcn_exp2f(-s);   // v_exp_f32 with neg modifier
        if constexpr (SET == 0) {
            const float4 C = lds[j * 3 + 2];    // b2,-,-,-
            a0 = fmaf(t0, B.z * e, a0);
            a1 = fmaf(t1, B.w * e, a1);
            a2 = fmaf(t2, C.x * e, a2);
        } else {
            constexpr int K = SET - 1;
            float tk = (K == 0) ? t0 : (K == 1 ? t1 : t2);
            a0 = fmaf(B.z, e, a0);              // u  = e @ h
            a1 = fmaf(tk, B.w * e, a1);         // du = (-2 diff d e) @ h
        }
    }

    if constexpr (SET == 0) {
        out[i]         = a0;   // ux
        out[N + i]     = a1;   // uy
        out[2 * N + i] = a2;   // uz
    } else {
        out[(2 * SET + 1) * N + i] = a0;  // P/Q/R
        out[(2 * SET + 2) * N + i] = a1;  // Px/Qy/Rz
    }
}

__global__ __launch_bounds__(256) void srbf_kernel(
    const float* x,
    const float* h1, const float* c1, const float* w1,
    const float* h2, const float* c2, const float* w2,
    const float* h3, const float* c3, const float* w3,
    const float* h4, const float* c4, const float* w4,
    float* out, int N, int N1)
{
    extern __shared__ float4 lds[];
    switch (blockIdx.y) {
    case 0: srbf_body<0>(x, h1, c1, w1, out, N, N1, lds); break;
    case 1: srbf_body<1>(x, h2, c2, w2, out, N, N1, lds); break;
    case 2: srbf_body<2>(x, h3, c3, w3, out, N, N1, lds); break;
    case 3: srbf_body<3>(x, h4, c4, w4, out, N, N1, lds); break;
    }
}

extern "C" void kernel_launch(void* const* d_in, const int* in_sizes, int n_in,
                              void* d_out, int out_size, void* d_ws, size_t ws_size,
                              hipStream_t stream)
{
    const float* x = (const float*)d_in[0];
    const int N  = in_sizes[0] / 3;   // 32768
    const int N1 = in_sizes[1];       // 1024

    dim3 grid(N / 256, 4);
    size_t lds_bytes = (size_t)N1 * 3 * sizeof(float4);  // worst case (SET 0): 48 KiB
    srbf_kernel<<<grid, 256, lds_bytes, stream>>>(
        x,
        (const float*)d_in[1],  (const float*)d_in[2],  (const float*)d_in[3],
        (const float*)d_in[4],  (const float*)d_in[5],  (const float*)d_in[6],
        (const float*)d_in[7],  (const float*)d_in[8],  (const float*)d_in[9],
        (const float*)d_in[10], (const float*)d_in[11], (const float*)d_in[12],
        (float*)d_out, N, N1);
}

// Round 2
// 42.396 us; speedup vs baseline: 1.2736x; 1.2736x over previous
//
#include <hip/hip_runtime.h>

// e = exp(-((x-cx)^2 w0^2 + ...)) with w' = w*sqrt(log2 e):
//   t_k = fma(x_k, w'_k, -c_k w'_k);  e = exp2(-(t0^2+t1^2+t2^2))
// du_k = -2 x1_k w_k^2 h e = t_k * (NEG_2LN2 * h * w'_k) * e
typedef float v2f __attribute__((ext_vector_type(2)));

static constexpr float SQRT_LOG2E = 1.2011224087864498f;   // sqrt(log2(e))
static constexpr float NEG_2LN2   = -1.3862943611198906f;  // -2*ln(2)

__device__ __forceinline__ v2f sp(float s) { return (v2f){s, s}; }
__device__ __forceinline__ v2f vfma(v2f a, v2f b, v2f c) {
    return __builtin_elementwise_fma(a, b, c);
}

template <int SET>  // 0: ux,uy,uz   1: P,Px   2: Q,Qy   3: R,Rz
__device__ __forceinline__ void srbf_body(
    const float* __restrict__ x, const float* __restrict__ h,
    const float* __restrict__ c, const float* __restrict__ w,
    float* __restrict__ dst, int N, int jbase, int jcount, float4* lds)
{
    constexpr int REC = (SET == 0) ? 3 : 2;       // float4 records per center
    constexpr int OB  = (SET == 0) ? 0 : (2 * SET + 1);  // output row base
    const int tid = threadIdx.x;

    // ---- stage per-center constants for this j-chunk into LDS ----
    for (int jj = tid; jj < jcount; jj += 256) {
        const int gj = jbase + jj;
        float hj  = h[gj];
        float w0  = w[3 * gj + 0] * SQRT_LOG2E;
        float w1  = w[3 * gj + 1] * SQRT_LOG2E;
        float w2  = w[3 * gj + 2] * SQRT_LOG2E;
        float cw0 = -c[3 * gj + 0] * w0;
        float cw1 = -c[3 * gj + 1] * w1;
        float cw2 = -c[3 * gj + 2] * w2;
        if constexpr (SET == 0) {
            lds[jj * 3 + 0] = make_float4(w0, w1, w2, cw0);
            lds[jj * 3 + 1] = make_float4(cw1, cw2, NEG_2LN2 * hj * w0, NEG_2LN2 * hj * w1);
            lds[jj * 3 + 2] = make_float4(NEG_2LN2 * hj * w2, 0.f, 0.f, 0.f);
        } else {
            constexpr int K = SET - 1;
            float wk = (K == 0) ? w0 : (K == 1 ? w1 : w2);
            lds[jj * 2 + 0] = make_float4(w0, w1, w2, cw0);
            lds[jj * 2 + 1] = make_float4(cw1, cw2, hj, NEG_2LN2 * hj * wk);
        }
    }
    __syncthreads();

    // ---- 4 points per thread: two v2f groups (i0,i0+256) and (i0+512,i0+768)
    const int i0 = blockIdx.x * 1024 + tid;
    v2f px[2], py[2], pz[2];
#pragma unroll
    for (int g = 0; g < 2; ++g) {
        const int ia = i0 + 512 * g, ib = ia + 256;
        px[g] = (v2f){x[3 * ia + 0], x[3 * ib + 0]};
        py[g] = (v2f){x[3 * ia + 1], x[3 * ib + 1]};
        pz[g] = (v2f){x[3 * ia + 2], x[3 * ib + 2]};
    }

    v2f a0[2] = {sp(0.f), sp(0.f)};
    v2f a1[2] = {sp(0.f), sp(0.f)};
    v2f a2[2] = {sp(0.f), sp(0.f)};

#pragma unroll 2
    for (int jj = 0; jj < jcount; ++jj) {
        const float4 A = lds[jj * REC + 0];   // w0,w1,w2,cw0
        const float4 B = lds[jj * REC + 1];   // cw1,cw2,(b0|h),(b1|b)
        float b2c = 0.f;
        if constexpr (SET == 0) b2c = lds[jj * 3 + 2].x;
#pragma unroll
        for (int g = 0; g < 2; ++g) {
            v2f t0 = vfma(px[g], sp(A.x), sp(A.w));
            v2f t1 = vfma(py[g], sp(A.y), sp(B.x));
            v2f t2 = vfma(pz[g], sp(A.z), sp(B.y));
            v2f s  = vfma(t0, t0, vfma(t1, t1, t2 * t2));
            v2f e  = (v2f){__builtin_amdgcn_exp2f(-s.x),
                           __builtin_amdgcn_exp2f(-s.y)};
            if constexpr (SET == 0) {
                a0[g] = vfma(t0, sp(B.z) * e, a0[g]);
                a1[g] = vfma(t1, sp(B.w) * e, a1[g]);
                a2[g] = vfma(t2, sp(b2c) * e, a2[g]);
            } else {
                constexpr int K = SET - 1;
                v2f tk = (K == 0) ? t0 : (K == 1 ? t1 : t2);
                a0[g] = vfma(sp(B.z), e, a0[g]);          // u  = e @ h
                a1[g] = vfma(tk, sp(B.w) * e, a1[g]);     // du
            }
        }
    }

#pragma unroll
    for (int g = 0; g < 2; ++g) {
        const int ia = i0 + 512 * g, ib = ia + 256;
        dst[(OB + 0) * N + ia] = a0[g].x;  dst[(OB + 0) * N + ib] = a0[g].y;
        dst[(OB + 1) * N + ia] = a1[g].x;  dst[(OB + 1) * N + ib] = a1[g].y;
        if constexpr (SET == 0) {
            dst[2 * N + ia] = a2[g].x;     dst[2 * N + ib] = a2[g].y;
        }
    }
}

__global__ __launch_bounds__(256) void srbf_kernel(
    const float* x,
    const float* h1, const float* c1, const float* w1,
    const float* h2, const float* c2, const float* w2,
    const float* h3, const float* c3, const float* w3,
    const float* h4, const float* c4, const float* w4,
    float* out, float* ws, int N, int jcount, int split)
{
    extern __shared__ float4 lds[];
    const int jbase = blockIdx.y * jcount;
    float* dst = split ? (ws + (size_t)blockIdx.y * 9 * N) : out;
    switch (blockIdx.z) {
    case 0: srbf_body<0>(x, h1, c1, w1, dst, N, jbase, jcount, lds); break;
    case 1: srbf_body<1>(x, h2, c2, w2, dst, N, jbase, jcount, lds); break;
    case 2: srbf_body<2>(x, h3, c3, w3, dst, N, jbase, jcount, lds); break;
    case 3: srbf_body<3>(x, h4, c4, w4, dst, N, jbase, jcount, lds); break;
    }
}

__global__ __launch_bounds__(256) void reduce_kernel(
    const float* __restrict__ ws, float* __restrict__ out, int total)
{
    const int i = blockIdx.x * 256 + threadIdx.x;
    if (i < total)
        out[i] = (ws[i] + ws[total + i]) + (ws[2 * total + i] + ws[3 * total + i]);
}

extern "C" void kernel_launch(void* const* d_in, const int* in_sizes, int n_in,
                              void* d_out, int out_size, void* d_ws, size_t ws_size,
                              hipStream_t stream)
{
    const float* x = (const float*)d_in[0];
    const int N  = in_sizes[0] / 3;   // 32768
    const int N1 = in_sizes[1];       // 1024

    const size_t partial_bytes = (size_t)4 * 9 * N * sizeof(float);
    const bool split = ws_size >= partial_bytes;
    const int JC = split ? 4 : 1;
    const int jcount = N1 / JC;

    dim3 grid(N / 1024, JC, 4);
    const size_t lds_bytes = (size_t)jcount * 3 * sizeof(float4);
    srbf_kernel<<<grid, 256, lds_bytes, stream>>>(
        x,
        (const float*)d_in[1],  (const float*)d_in[2],  (const float*)d_in[3],
        (const float*)d_in[4],  (const float*)d_in[5],  (const float*)d_in[6],
        (const float*)d_in[7],  (const float*)d_in[8],  (const float*)d_in[9],
        (const float*)d_in[10], (const float*)d_in[11], (const float*)d_in[12],
        (float*)d_out, (float*)d_ws, N, jcount, split ? 1 : 0);

    if (split) {
        const int total = 9 * N;
        reduce_kernel<<<(total + 255) / 256, 256, 0, stream>>>(
            (const float*)d_ws, (float*)d_out, total);
    }
}

// Round 3
// 39.169 us; speedup vs baseline: 1.3785x; 1.0824x over previous
//
#include <hip/hip_runtime.h>

// e = exp(-((x-cx)^2 w0^2 + ...)) with w' = w*sqrt(log2 e):
//   t_k = fma(x_k, w'_k, -c_k w'_k);  e = exp2(-(t0^2+t1^2+t2^2))
// du_k = -2 x1_k w_k^2 h e = t_k * (NEG_2LN2 * h * w'_k) * e
typedef float v2f __attribute__((ext_vector_type(2)));

static constexpr float SQRT_LOG2E = 1.2011224087864498f;   // sqrt(log2(e))
static constexpr float NEG_2LN2   = -1.3862943611198906f;  // -2*ln(2)

__device__ __forceinline__ v2f sp(float s) { return (v2f){s, s}; }
__device__ __forceinline__ v2f vfma(v2f a, v2f b, v2f c) {
    return __builtin_elementwise_fma(a, b, c);
}

template <int SET>  // 0: ux,uy,uz   1: P,Px   2: Q,Qy   3: R,Rz
__device__ __forceinline__ void srbf_body(
    const float* __restrict__ x, const float* __restrict__ h,
    const float* __restrict__ c, const float* __restrict__ w,
    float* __restrict__ dst, int N, int jbase, int jcount, float4* lds)
{
    constexpr int REC = (SET == 0) ? 3 : 2;              // float4 records per center
    constexpr int OB  = (SET == 0) ? 0 : (2 * SET + 1);  // output row base
    const int tid = threadIdx.x;

    // ---- stage per-center constants for this j-chunk into LDS ----
    for (int jj = tid; jj < jcount; jj += 256) {
        const int gj = jbase + jj;
        float hj  = h[gj];
        float w0  = w[3 * gj + 0] * SQRT_LOG2E;
        float w1  = w[3 * gj + 1] * SQRT_LOG2E;
        float w2  = w[3 * gj + 2] * SQRT_LOG2E;
        float cw0 = -c[3 * gj + 0] * w0;
        float cw1 = -c[3 * gj + 1] * w1;
        float cw2 = -c[3 * gj + 2] * w2;
        if constexpr (SET == 0) {
            lds[jj * 3 + 0] = make_float4(w0, w1, w2, cw0);
            lds[jj * 3 + 1] = make_float4(cw1, cw2, NEG_2LN2 * hj * w0, NEG_2LN2 * hj * w1);
            lds[jj * 3 + 2] = make_float4(NEG_2LN2 * hj * w2, 0.f, 0.f, 0.f);
        } else {
            constexpr int K = SET - 1;
            float wk = (K == 0) ? w0 : (K == 1 ? w1 : w2);
            lds[jj * 2 + 0] = make_float4(w0, w1, w2, cw0);
            lds[jj * 2 + 1] = make_float4(cw1, cw2, hj, NEG_2LN2 * hj * wk);
        }
    }
    __syncthreads();

    // ---- 4 points per thread: two v2f groups (i0,i0+256) and (i0+512,i0+768)
    const int i0 = blockIdx.x * 1024 + tid;
    v2f px[2], py[2], pz[2];
#pragma unroll
    for (int g = 0; g < 2; ++g) {
        const int ia = i0 + 512 * g, ib = ia + 256;
        px[g] = (v2f){x[3 * ia + 0], x[3 * ib + 0]};
        py[g] = (v2f){x[3 * ia + 1], x[3 * ib + 1]};
        pz[g] = (v2f){x[3 * ia + 2], x[3 * ib + 2]};
    }

    v2f a0[2] = {sp(0.f), sp(0.f)};
    v2f a1[2] = {sp(0.f), sp(0.f)};
    v2f a2[2] = {sp(0.f), sp(0.f)};

#pragma unroll 4
    for (int jj = 0; jj < jcount; ++jj) {
        const float4 A = lds[jj * REC + 0];   // w0,w1,w2,cw0
        const float4 B = lds[jj * REC + 1];   // cw1,cw2,(b0|h),(b1|b)
        float b2c = 0.f;
        if constexpr (SET == 0) b2c = lds[jj * 3 + 2].x;
#pragma unroll
        for (int g = 0; g < 2; ++g) {
            v2f t0 = vfma(px[g], sp(A.x), sp(A.w));
            v2f t1 = vfma(py[g], sp(A.y), sp(B.x));
            v2f t2 = vfma(pz[g], sp(A.z), sp(B.y));
            v2f s  = vfma(t0, t0, vfma(t1, t1, t2 * t2));
            v2f e  = (v2f){__builtin_amdgcn_exp2f(-s.x),
                           __builtin_amdgcn_exp2f(-s.y)};
            if constexpr (SET == 0) {
                a0[g] = vfma(t0, sp(B.z) * e, a0[g]);
                a1[g] = vfma(t1, sp(B.w) * e, a1[g]);
                a2[g] = vfma(t2, sp(b2c) * e, a2[g]);
            } else {
                constexpr int K = SET - 1;
                v2f tk = (K == 0) ? t0 : (K == 1 ? t1 : t2);
                a0[g] = vfma(sp(B.z), e, a0[g]);          // u  = e @ h
                a1[g] = vfma(tk, sp(B.w) * e, a1[g]);     // du
            }
        }
    }

#pragma unroll
    for (int g = 0; g < 2; ++g) {
        const int ia = i0 + 512 * g, ib = ia + 256;
        dst[(OB + 0) * N + ia] = a0[g].x;  dst[(OB + 0) * N + ib] = a0[g].y;
        dst[(OB + 1) * N + ia] = a1[g].x;  dst[(OB + 1) * N + ib] = a1[g].y;
        if constexpr (SET == 0) {
            dst[2 * N + ia] = a2[g].x;     dst[2 * N + ib] = a2[g].y;
        }
    }
}

__global__ __launch_bounds__(256) void srbf_kernel(
    const float* x,
    const float* h1, const float* c1, const float* w1,
    const float* h2, const float* c2, const float* w2,
    const float* h3, const float* c3, const float* w3,
    const float* h4, const float* c4, const float* w4,
    float* out, float* ws, int N, int jcount, int split)
{
    extern __shared__ float4 lds[];
    const int jbase = blockIdx.y * jcount;
    float* dst = (split > 1) ? (ws + (size_t)blockIdx.y * 9 * N) : out;
    switch (blockIdx.z) {
    case 0: srbf_body<0>(x, h1, c1, w1, dst, N, jbase, jcount, lds); break;
    case 1: srbf_body<1>(x, h2, c2, w2, dst, N, jbase, jcount, lds); break;
    case 2: srbf_body<2>(x, h3, c3, w3, dst, N, jbase, jcount, lds); break;
    case 3: srbf_body<3>(x, h4, c4, w4, dst, N, jbase, jcount, lds); break;
    }
}

__global__ __launch_bounds__(256) void reduce_kernel(
    const float4* __restrict__ ws, float4* __restrict__ out,
    int total4, int split)
{
    const int i = blockIdx.x * 256 + threadIdx.x;
    if (i < total4) {
        float4 acc = ws[i];
#pragma unroll 8
        for (int p = 1; p < split; ++p) {
            const float4 v = ws[(size_t)p * total4 + i];
            acc.x += v.x; acc.y += v.y; acc.z += v.z; acc.w += v.w;
        }
        out[i] = acc;
    }
}

extern "C" void kernel_launch(void* const* d_in, const int* in_sizes, int n_in,
                              void* d_out, int out_size, void* d_ws, size_t ws_size,
                              hipStream_t stream)
{
    const float* x = (const float*)d_in[0];
    const int N  = in_sizes[0] / 3;   // 32768
    const int N1 = in_sizes[1];       // 1024

    // pick the largest j-split whose partials fit in the workspace
    int split = 1;
    for (int s = 8; s >= 2; s >>= 1) {
        if (ws_size >= (size_t)s * 9 * N * sizeof(float) && (N1 % s) == 0) {
            split = s; break;
        }
    }
    const int jcount = N1 / split;

    dim3 grid(N / 1024, split, 4);
    const size_t lds_bytes = (size_t)jcount * 3 * sizeof(float4);
    srbf_kernel<<<grid, 256, lds_bytes, stream>>>(
        x,
        (const float*)d_in[1],  (const float*)d_in[2],  (const float*)d_in[3],
        (const float*)d_in[4],  (const float*)d_in[5],  (const float*)d_in[6],
        (const float*)d_in[7],  (const float*)d_in[8],  (const float*)d_in[9],
        (const float*)d_in[10], (const float*)d_in[11], (const float*)d_in[12],
        (float*)d_out, (float*)d_ws, N, jcount, split);

    if (split > 1) {
        const int total4 = 9 * N / 4;
        reduce_kernel<<<(total4 + 255) / 256, 256, 0, stream>>>(
            (const float4*)d_ws, (float4*)d_out, total4, split);
    }
}